// Round 4
// baseline (4268.065 us; speedup 1.0000x reference)
//
#include <hip/hip_runtime.h>
#include <hip/hip_fp16.h>

#define TT 2048
#define BB 64
#define HH 128

typedef _Float16 f16x8 __attribute__((ext_vector_type(8)));
typedef float f32x4 __attribute__((ext_vector_type(4)));

__device__ __forceinline__ float sigm(float x) {
    return __builtin_amdgcn_rcpf(1.0f + __expf(-x));
}
__device__ __forceinline__ float tanh_f(float x) {
    return 1.0f - 2.0f * __builtin_amdgcn_rcpf(1.0f + __expf(2.0f * x));
}
// LDS-only barrier: does NOT drain vmcnt, so global prefetches/stores stay in
// flight across steps (HIP __syncthreads would emit s_waitcnt vmcnt(0)).
__device__ __forceinline__ void bar_lds() {
    asm volatile("s_waitcnt lgkmcnt(0)\n\ts_barrier" ::: "memory");
}

// Batched-M recurrence: block = 8 batches, 8 waves. Wave w owns units
// [16w,16w+16); lane: c=lane&15, q=lane>>4. MFMA 16x16x32_f16:
//   A[m=c][k=q*8+j]  (m = batch; rows 8..15 padded zero)
//   B[k=q*8+j][n=c]  (n = unit-in-tile; N-tile t2 = gate)
//   C col=c (unit), row m=4q+r (batch; q<2 real)
// h crosses steps via padded LDS Hb[2][16][136] fp16, one LDS barrier/step.

// ---------------- x transpose: [64][2048] -> [2048][64] ----------------
__global__ void k_xt(const float* __restrict__ x, float* __restrict__ xT) {
    int idx = blockIdx.x * 256 + threadIdx.x;  // 131072 threads
    int t = idx >> 6, b = idx & 63;
    xT[idx] = x[b * TT + t];
}

// ---------------- layer 0 ----------------
__global__ __launch_bounds__(512, 1) void k_layer0(
    const float* __restrict__ xT, const int* __restrict__ lengths,
    const float* __restrict__ ff_w, const float* __restrict__ ff_b,
    const float* __restrict__ W_ih0, const float* __restrict__ W_hh0,
    const float* __restrict__ b0, _Float16* __restrict__ h1g) {
    const int blk = blockIdx.x;
    const int tid = threadIdx.x;
    const int w = tid >> 6;
    const int lane = tid & 63;
    const int c = lane & 15;
    const int q = lane >> 4;
    const int u = 16 * w + c;
    __shared__ _Float16 Hb[2][16][136];

    int lenmax = 1;
#pragma unroll
    for (int i = 0; i < 8; ++i) lenmax = max(lenmax, lengths[8 * blk + i]);

    f16x8 Bf[4][4];
    float v[4], u0[4];
#pragma unroll
    for (int t2 = 0; t2 < 4; ++t2) {
        const int r = t2 * HH + u;
        const float* wr = W_hh0 + r * HH;
#pragma unroll
        for (int kt = 0; kt < 4; ++kt) {
            const float4* p4 = (const float4*)(wr + kt * 32 + q * 8);
            float4 w0 = p4[0], w1 = p4[1];
            f16x8 bf;
            bf[0] = (_Float16)w0.x; bf[1] = (_Float16)w0.y;
            bf[2] = (_Float16)w0.z; bf[3] = (_Float16)w0.w;
            bf[4] = (_Float16)w1.x; bf[5] = (_Float16)w1.y;
            bf[6] = (_Float16)w1.z; bf[7] = (_Float16)w1.w;
            Bf[t2][kt] = bf;
        }
        const float* wi = W_ih0 + r * HH;
        float vv = 0.f, uu = 0.f;
        for (int k = 0; k < HH; ++k) { vv += wi[k] * ff_w[k]; uu += wi[k] * ff_b[k]; }
        v[t2] = vv;
        u0[t2] = uu + b0[r];
    }
    for (int i = tid; i < 2 * 16 * 136; i += 512) ((_Float16*)Hb)[i] = (_Float16)0.f;

    const float* xbase = xT + 8 * blk + 4 * q;
    float4 xp0 = *(const float4*)(xbase);
    float4 xp1 = (lenmax > 1) ? *(const float4*)(xbase + 64) : xp0;
    float cst[4] = {0.f, 0.f, 0.f, 0.f};
    __syncthreads();

#define L0_STEP(T_, RB_, XP_)                                                     \
    do {                                                                          \
        f16x8 av[4];                                                              \
        _Pragma("unroll") for (int kt = 0; kt < 4; ++kt)                          \
            av[kt] = (f16x8){0, 0, 0, 0, 0, 0, 0, 0};                             \
        if (c < 8) {                                                              \
            _Pragma("unroll") for (int kt = 0; kt < 4; ++kt)                      \
                av[kt] = *(const f16x8*)&Hb[RB_][c][kt * 32 + q * 8];             \
        }                                                                         \
        f32x4 acc[4];                                                             \
        _Pragma("unroll") for (int t2 = 0; t2 < 4; ++t2) {                        \
            _Pragma("unroll") for (int r = 0; r < 4; ++r)                         \
                acc[t2][r] = XP_[r] * v[t2] + u0[t2];                             \
        }                                                                         \
        {                                                                         \
            int tp = ((T_) + 2 < lenmax) ? (T_) + 2 : lenmax - 1;                 \
            XP_ = *(const float4*)(xbase + (size_t)tp * 64);                      \
        }                                                                         \
        _Pragma("unroll") for (int t2 = 0; t2 < 4; ++t2) {                        \
            _Pragma("unroll") for (int kt = 0; kt < 4; ++kt)                      \
                acc[t2] = __builtin_amdgcn_mfma_f32_16x16x32_f16(                 \
                    av[kt], Bf[t2][kt], acc[t2], 0, 0, 0);                        \
        }                                                                         \
        float hn[4];                                                              \
        _Pragma("unroll") for (int r = 0; r < 4; ++r) {                           \
            float gi = sigm(acc[0][r]), gf = sigm(acc[1][r]);                     \
            float gg = tanh_f(acc[2][r]), go = sigm(acc[3][r]);                   \
            cst[r] = gf * cst[r] + gi * gg;                                       \
            hn[r] = go * tanh_f(cst[r]);                                          \
        }                                                                         \
        if (q < 2) {                                                              \
            _Pragma("unroll") for (int r = 0; r < 4; ++r) {                       \
                Hb[(RB_) ^ 1][4 * q + r][u] = (_Float16)hn[r];                    \
                h1g[((size_t)(T_)*BB + 8 * blk + 4 * q + r) * HH + u] =           \
                    (_Float16)hn[r];                                              \
            }                                                                     \
        }                                                                         \
        bar_lds();                                                                \
    } while (0)

    int t = 0;
    for (; t + 1 < lenmax; t += 2) {
        L0_STEP(t, 0, xp0);
        L0_STEP(t + 1, 1, xp1);
    }
    if (t < lenmax) L0_STEP(t, 0, xp0);
#undef L0_STEP
}

// ---------------- layer 1 (+ fused masked mean/max/last pooling) ----------------
__global__ __launch_bounds__(512, 1) void k_layer1(
    const _Float16* __restrict__ h1g, const int* __restrict__ lengths,
    const float* __restrict__ W_ih1, const float* __restrict__ W_hh1,
    const float* __restrict__ b1, float* __restrict__ pooled) {
    const int blk = blockIdx.x;
    const int tid = threadIdx.x;
    const int w = tid >> 6;
    const int lane = tid & 63;
    const int c = lane & 15;
    const int q = lane >> 4;
    const int u = 16 * w + c;
    __shared__ _Float16 Hb[2][16][136];

    int lenmax = 1;
#pragma unroll
    for (int i = 0; i < 8; ++i) lenmax = max(lenmax, lengths[8 * blk + i]);
    int lenr[4];
#pragma unroll
    for (int r = 0; r < 4; ++r)
        lenr[r] = (q < 2) ? lengths[8 * blk + 4 * q + r] : 1;

    f16x8 Bh[4][4], Bi[4][4];
    float bia[4];
#pragma unroll
    for (int t2 = 0; t2 < 4; ++t2) {
        const int r = t2 * HH + u;
        const float* wh = W_hh1 + r * HH;
        const float* wi = W_ih1 + r * HH;
#pragma unroll
        for (int kt = 0; kt < 4; ++kt) {
            const float4* p4 = (const float4*)(wh + kt * 32 + q * 8);
            float4 w0 = p4[0], w1 = p4[1];
            f16x8 bf;
            bf[0] = (_Float16)w0.x; bf[1] = (_Float16)w0.y;
            bf[2] = (_Float16)w0.z; bf[3] = (_Float16)w0.w;
            bf[4] = (_Float16)w1.x; bf[5] = (_Float16)w1.y;
            bf[6] = (_Float16)w1.z; bf[7] = (_Float16)w1.w;
            Bh[t2][kt] = bf;
            const float4* q4 = (const float4*)(wi + kt * 32 + q * 8);
            float4 i0 = q4[0], i1 = q4[1];
            f16x8 bg;
            bg[0] = (_Float16)i0.x; bg[1] = (_Float16)i0.y;
            bg[2] = (_Float16)i0.z; bg[3] = (_Float16)i0.w;
            bg[4] = (_Float16)i1.x; bg[5] = (_Float16)i1.y;
            bg[6] = (_Float16)i1.z; bg[7] = (_Float16)i1.w;
            Bi[t2][kt] = bg;
        }
        bia[t2] = b1[r];
    }
    for (int i = tid; i < 2 * 16 * 136; i += 512) ((_Float16*)Hb)[i] = (_Float16)0.f;

    // A-ih prefetch buffers (h1 rows, 2 steps ahead)
    f16x8 P0[4], P1[4];
#pragma unroll
    for (int kt = 0; kt < 4; ++kt) {
        P0[kt] = (f16x8){0, 0, 0, 0, 0, 0, 0, 0};
        P1[kt] = (f16x8){0, 0, 0, 0, 0, 0, 0, 0};
    }
    if (c < 8) {
        const _Float16* a0 = h1g + ((size_t)0 * BB + 8 * blk + c) * HH + q * 8;
        int t1i = (lenmax > 1) ? 1 : 0;
        const _Float16* a1 = h1g + ((size_t)t1i * BB + 8 * blk + c) * HH + q * 8;
#pragma unroll
        for (int kt = 0; kt < 4; ++kt) {
            P0[kt] = *(const f16x8*)(a0 + kt * 32);
            P1[kt] = *(const f16x8*)(a1 + kt * 32);
        }
    }
    float cst[4] = {0.f, 0.f, 0.f, 0.f};
    float mean[4] = {0.f, 0.f, 0.f, 0.f};
    float mx[4] = {-1e30f, -1e30f, -1e30f, -1e30f};
    float lastv[4] = {0.f, 0.f, 0.f, 0.f};
    __syncthreads();

#define L1_STEP(T_, RB_, P_)                                                      \
    do {                                                                          \
        f16x8 av[4];                                                              \
        _Pragma("unroll") for (int kt = 0; kt < 4; ++kt)                          \
            av[kt] = (f16x8){0, 0, 0, 0, 0, 0, 0, 0};                             \
        if (c < 8) {                                                              \
            _Pragma("unroll") for (int kt = 0; kt < 4; ++kt)                      \
                av[kt] = *(const f16x8*)&Hb[RB_][c][kt * 32 + q * 8];             \
        }                                                                         \
        f32x4 acc[4];                                                             \
        _Pragma("unroll") for (int t2 = 0; t2 < 4; ++t2) {                        \
            acc[t2][0] = bia[t2]; acc[t2][1] = bia[t2];                           \
            acc[t2][2] = bia[t2]; acc[t2][3] = bia[t2];                           \
        }                                                                         \
        _Pragma("unroll") for (int t2 = 0; t2 < 4; ++t2) {                        \
            _Pragma("unroll") for (int kt = 0; kt < 4; ++kt)                      \
                acc[t2] = __builtin_amdgcn_mfma_f32_16x16x32_f16(                 \
                    P_[kt], Bi[t2][kt], acc[t2], 0, 0, 0);                        \
        }                                                                         \
        if (c < 8) {                                                              \
            int tp = ((T_) + 2 < lenmax) ? (T_) + 2 : lenmax - 1;                 \
            const _Float16* ap =                                                  \
                h1g + ((size_t)tp * BB + 8 * blk + c) * HH + q * 8;               \
            _Pragma("unroll") for (int kt = 0; kt < 4; ++kt)                      \
                P_[kt] = *(const f16x8*)(ap + kt * 32);                           \
        }                                                                         \
        _Pragma("unroll") for (int t2 = 0; t2 < 4; ++t2) {                        \
            _Pragma("unroll") for (int kt = 0; kt < 4; ++kt)                      \
                acc[t2] = __builtin_amdgcn_mfma_f32_16x16x32_f16(                 \
                    av[kt], Bh[t2][kt], acc[t2], 0, 0, 0);                        \
        }                                                                         \
        _Pragma("unroll") for (int r = 0; r < 4; ++r) {                           \
            float gi = sigm(acc[0][r]), gf = sigm(acc[1][r]);                     \
            float gg = tanh_f(acc[2][r]), go = sigm(acc[3][r]);                   \
            cst[r] = gf * cst[r] + gi * gg;                                       \
            float hn = go * tanh_f(cst[r]);                                       \
            if ((T_) < lenr[r]) {                                                 \
                mean[r] += hn;                                                    \
                mx[r] = fmaxf(mx[r], hn);                                         \
            }                                                                     \
            if ((T_) == lenr[r] - 1) lastv[r] = hn;                               \
            if (q < 2) Hb[(RB_) ^ 1][4 * q + r][u] = (_Float16)hn;                \
        }                                                                         \
        bar_lds();                                                                \
    } while (0)

    int t = 0;
    for (; t + 1 < lenmax; t += 2) {
        L1_STEP(t, 0, P0);
        L1_STEP(t + 1, 1, P1);
    }
    if (t < lenmax) L1_STEP(t, 0, P0);
#undef L1_STEP

    if (q < 2) {
#pragma unroll
        for (int r = 0; r < 4; ++r) {
            int b = 8 * blk + 4 * q + r;
            pooled[b * 384 + u] = mean[r] / (float)lenr[r];
            pooled[b * 384 + 128 + u] = mx[r];
            pooled[b * 384 + 256 + u] = lastv[r];
        }
    }
}

// ---------------- head: [B,3H] @ [3H,C]^T + bias ----------------
__global__ __launch_bounds__(448) void k_head(
    const float* __restrict__ pooled, const float* __restrict__ lin_w,
    const float* __restrict__ lin_b, float* __restrict__ out) {
    int tid = threadIdx.x;  // 448 = 64*7
    int b = tid / 7, cc = tid % 7;
    const float* p = pooled + b * 384;
    const float* wr = lin_w + cc * 384;
    float a0 = 0.f, a1 = 0.f, a2 = 0.f, a3 = 0.f;
#pragma unroll
    for (int k = 0; k < 384; k += 4) {
        a0 += p[k + 0] * wr[k + 0];
        a1 += p[k + 1] * wr[k + 1];
        a2 += p[k + 2] * wr[k + 2];
        a3 += p[k + 3] * wr[k + 3];
    }
    out[tid] = lin_b[cc] + ((a0 + a1) + (a2 + a3));
}

extern "C" void kernel_launch(void* const* d_in, const int* in_sizes, int n_in,
                              void* d_out, int out_size, void* d_ws, size_t ws_size,
                              hipStream_t stream) {
    const float* x     = (const float*)d_in[0];
    const int*   lens  = (const int*)d_in[1];
    const float* ff_w  = (const float*)d_in[2];
    const float* ff_b  = (const float*)d_in[3];
    const float* W_ih0 = (const float*)d_in[4];
    const float* W_hh0 = (const float*)d_in[5];
    const float* b0    = (const float*)d_in[6];
    const float* W_ih1 = (const float*)d_in[7];
    const float* W_hh1 = (const float*)d_in[8];
    const float* b1    = (const float*)d_in[9];
    const float* lin_w = (const float*)d_in[10];
    const float* lin_b = (const float*)d_in[11];
    float* out = (float*)d_out;

    char* ws = (char*)d_ws;
    float* xT = (float*)ws;                                   // 2048*64 + 64 pad floats
    size_t off1 = ((size_t)(TT * BB + 64) * 4 + 255) & ~(size_t)255;  // 524544
    _Float16* h1g = (_Float16*)(ws + off1);                   // [T][64][128] fp16 = 32 MB
    float* pooled = (float*)(ws + off1 + (size_t)TT * BB * HH * 2);   // [64*384]

    k_xt<<<dim3((TT * BB) / 256), dim3(256), 0, stream>>>(x, xT);
    k_layer0<<<dim3(8), dim3(512), 0, stream>>>(xT, lens, ff_w, ff_b, W_ih0, W_hh0, b0, h1g);
    k_layer1<<<dim3(8), dim3(512), 0, stream>>>(h1g, lens, W_ih1, W_hh1, b1, pooled);
    k_head<<<dim3(1), dim3(448), 0, stream>>>(pooled, lin_w, lin_b, out);
}

// Round 5
// 2460.247 us; speedup vs baseline: 1.7348x; 1.7348x over previous
//
#include <hip/hip_runtime.h>
#include <hip/hip_fp16.h>

#define TT 2048
#define BB 64
#define HH 128
#define GG 512  // 4H

typedef _Float16 f16x8 __attribute__((ext_vector_type(8)));
typedef _Float16 f16x4 __attribute__((ext_vector_type(4)));
typedef float f32x4 __attribute__((ext_vector_type(4)));

__device__ __forceinline__ float sigm(float x) {
    return __builtin_amdgcn_rcpf(1.0f + __expf(-x));
}
__device__ __forceinline__ float tanh_f(float x) {
    return 1.0f - 2.0f * __builtin_amdgcn_rcpf(1.0f + __expf(2.0f * x));
}
// LDS-only barrier: does NOT drain vmcnt -> per-step global stores (h1) and
// prefetch loads (g1) stay in flight across steps. HIP __syncthreads emits
// s_waitcnt vmcnt(0) which put ~900-1300 cyc of HBM latency on every step
// (the round-1..3 ~2000 cyc/step plateau).
__device__ __forceinline__ void bar_lds() {
    asm volatile("s_waitcnt lgkmcnt(0)\n\ts_barrier" ::: "memory");
}

// M=1 MFMA recurrence, 1 batch per block, 64 blocks (round-3 structure).
// mfma_f32_16x16x32_f16: A row m=0 = h (lanes c==0 read 4 masked ds_read_b128;
// other lanes' av regs stay 0 forever). N-tile t2 = gate, col c = unit-in-tile
// -> lane's 4 accumulators are the 4 gates of unit un = 16w+c, no exchange.

// ---------------- layer 0 recurrence ----------------
__global__ __launch_bounds__(512, 2) void k_lstm0(
    const float* __restrict__ x, const int* __restrict__ lengths,
    const float* __restrict__ ff_w, const float* __restrict__ ff_b,
    const float* __restrict__ W_ih0, const float* __restrict__ W_hh0,
    const float* __restrict__ b0, _Float16* __restrict__ h1) {
    const int b = blockIdx.x;
    const int tid = threadIdx.x;
    const int w = tid >> 6;
    const int lane = tid & 63;
    const int c = lane & 15;
    const int lh = lane >> 4;
    const int un = 16 * w + c;
    __shared__ float xs[TT];
    __shared__ _Float16 Hb[2][HH];

    for (int i = tid; i < TT; i += 512) xs[i] = x[b * TT + i];
    if (tid < 2 * HH) ((_Float16*)Hb)[tid] = (_Float16)0.f;

    f16x8 Bf[4][4];
    float v[4], u0[4];
#pragma unroll
    for (int t2 = 0; t2 < 4; ++t2) {
        const int r = t2 * HH + un;
        const float* wr = W_hh0 + r * HH;
#pragma unroll
        for (int kt = 0; kt < 4; ++kt) {
            const float4* p4 = (const float4*)(wr + kt * 32 + lh * 8);
            float4 w0 = p4[0], w1 = p4[1];
            f16x8 bf;
            bf[0] = (_Float16)w0.x; bf[1] = (_Float16)w0.y;
            bf[2] = (_Float16)w0.z; bf[3] = (_Float16)w0.w;
            bf[4] = (_Float16)w1.x; bf[5] = (_Float16)w1.y;
            bf[6] = (_Float16)w1.z; bf[7] = (_Float16)w1.w;
            Bf[t2][kt] = bf;
        }
        const float* wi = W_ih0 + r * HH;
        float vv = 0.f, uu = 0.f;
        for (int k = 0; k < HH; ++k) { vv += wi[k] * ff_w[k]; uu += wi[k] * ff_b[k]; }
        v[t2] = vv;
        u0[t2] = uu + b0[r];
    }
    float cst = 0.f;
    const int len = lengths[b];
    const bool ard = (c == 0);
    const bool wr16 = (lane < 16);
    f16x8 av[4];
#pragma unroll
    for (int kt = 0; kt < 4; ++kt) av[kt] = (f16x8){0, 0, 0, 0, 0, 0, 0, 0};
    __syncthreads();

#define L0_STEP(T_, RB_)                                                          \
    do {                                                                          \
        if (ard) {                                                                \
            _Pragma("unroll") for (int kt = 0; kt < 4; ++kt)                      \
                av[kt] = *(const f16x8*)&Hb[RB_][kt * 32 + lh * 8];               \
        }                                                                         \
        const float xt = xs[T_];                                                  \
        f32x4 acc[4];                                                             \
        _Pragma("unroll") for (int t2 = 0; t2 < 4; ++t2) {                        \
            acc[t2][0] = wr16 ? (xt * v[t2] + u0[t2]) : 0.f;                      \
            acc[t2][1] = 0.f; acc[t2][2] = 0.f; acc[t2][3] = 0.f;                 \
        }                                                                         \
        _Pragma("unroll") for (int t2 = 0; t2 < 4; ++t2) {                        \
            _Pragma("unroll") for (int kt = 0; kt < 4; ++kt)                      \
                acc[t2] = __builtin_amdgcn_mfma_f32_16x16x32_f16(                 \
                    av[kt], Bf[t2][kt], acc[t2], 0, 0, 0);                        \
        }                                                                         \
        float gi = sigm(acc[0][0]), gf = sigm(acc[1][0]);                         \
        float gg = tanh_f(acc[2][0]), go = sigm(acc[3][0]);                       \
        cst = gf * cst + gi * gg;                                                 \
        float hn = go * tanh_f(cst);                                              \
        if (wr16) {                                                               \
            Hb[(RB_) ^ 1][un] = (_Float16)hn;                                     \
            h1[((size_t)(T_)*BB + b) * HH + un] = (_Float16)hn;                   \
        }                                                                         \
        bar_lds();                                                                \
    } while (0)

    int t = 0;
    for (; t + 1 < len; t += 2) {
        L0_STEP(t, 0);
        L0_STEP(t + 1, 1);
    }
    if (t < len) L0_STEP(t, 0);
#undef L0_STEP
}

// ---------------- layer-1 input projection GEMM: [T*B,128] @ [128,512]^T + b1 -> fp16 ----------------
// Epilogue scatters into [row][unit][gate] order (pos = (n&127)*4 + n>>7) so
// k_lstm1's per-step C-init is ONE 8-byte load per real lane, coalesced.
__global__ __launch_bounds__(256, 2) void k_proj(
    const __half* __restrict__ h1, const float* __restrict__ W_ih1,
    const float* __restrict__ b1, __half* __restrict__ g1) {
    const int m0 = blockIdx.x * 64;
    const int n0 = blockIdx.y * 64;
    const int tid = threadIdx.x;
    const int tn = tid & 15, tm = tid >> 4;
    __shared__ float As[64 * 65];
    __shared__ float Ws[64 * 65];
    float acc[4][4];
#pragma unroll
    for (int i = 0; i < 4; ++i)
#pragma unroll
        for (int jj = 0; jj < 4; ++jj) acc[i][jj] = 0.f;

    for (int ko = 0; ko < HH; ko += 64) {
#pragma unroll
        for (int p = 0; p < 8; ++p) {
            int idx2 = tid + p * 256;
            int m = idx2 >> 5, kk2 = idx2 & 31;
            __half2 hv = *reinterpret_cast<const __half2*>(h1 + (m0 + m) * HH + ko + kk2 * 2);
            float2 f = __half22float2(hv);
            As[m * 65 + 2 * kk2 + 0] = f.x;
            As[m * 65 + 2 * kk2 + 1] = f.y;
        }
#pragma unroll
        for (int p = 0; p < 4; ++p) {
            int idx4 = tid + p * 256;
            int n = idx4 >> 4, kk4 = idx4 & 15;
            float4 wv = *reinterpret_cast<const float4*>(W_ih1 + (n0 + n) * HH + ko + kk4 * 4);
            Ws[n * 65 + 4 * kk4 + 0] = wv.x;
            Ws[n * 65 + 4 * kk4 + 1] = wv.y;
            Ws[n * 65 + 4 * kk4 + 2] = wv.z;
            Ws[n * 65 + 4 * kk4 + 3] = wv.w;
        }
        __syncthreads();
#pragma unroll 8
        for (int k = 0; k < 64; ++k) {
            float a0 = As[(4 * tm + 0) * 65 + k];
            float a1 = As[(4 * tm + 1) * 65 + k];
            float a2 = As[(4 * tm + 2) * 65 + k];
            float a3 = As[(4 * tm + 3) * 65 + k];
            float w0 = Ws[(4 * tn + 0) * 65 + k];
            float w1 = Ws[(4 * tn + 1) * 65 + k];
            float w2 = Ws[(4 * tn + 2) * 65 + k];
            float w3 = Ws[(4 * tn + 3) * 65 + k];
            acc[0][0] += a0 * w0; acc[0][1] += a0 * w1; acc[0][2] += a0 * w2; acc[0][3] += a0 * w3;
            acc[1][0] += a1 * w0; acc[1][1] += a1 * w1; acc[1][2] += a1 * w2; acc[1][3] += a1 * w3;
            acc[2][0] += a2 * w0; acc[2][1] += a2 * w1; acc[2][2] += a2 * w2; acc[2][3] += a2 * w3;
            acc[3][0] += a3 * w0; acc[3][1] += a3 * w1; acc[3][2] += a3 * w2; acc[3][3] += a3 * w3;
        }
        __syncthreads();
    }
    float bb[4];
#pragma unroll
    for (int q = 0; q < 4; ++q) bb[q] = b1[n0 + 4 * tn + q];
#pragma unroll
    for (int i = 0; i < 4; ++i) {
        int m = m0 + 4 * tm + i;
        __half* dst = g1 + (size_t)m * GG;
#pragma unroll
        for (int q = 0; q < 4; ++q) {
            int n = n0 + 4 * tn + q;
            int pos = ((n & 127) << 2) | (n >> 7);  // [unit][gate]
            dst[pos] = __float2half(acc[i][q] + bb[q]);
        }
    }
}

// ---------------- layer 1 recurrence + fused masked mean/max/last pooling ----------------
__global__ __launch_bounds__(512, 2) void k_lstm1(
    const _Float16* __restrict__ g1, const int* __restrict__ lengths,
    const float* __restrict__ W_hh1, float* __restrict__ pooled) {
    const int b = blockIdx.x;
    const int tid = threadIdx.x;
    const int w = tid >> 6;
    const int lane = tid & 63;
    const int c = lane & 15;
    const int lh = lane >> 4;
    const int un = 16 * w + c;
    __shared__ _Float16 Hb[2][HH];

    if (tid < 2 * HH) ((_Float16*)Hb)[tid] = (_Float16)0.f;

    f16x8 Bf[4][4];
#pragma unroll
    for (int t2 = 0; t2 < 4; ++t2) {
        const float* wr = W_hh1 + (t2 * HH + un) * HH;
#pragma unroll
        for (int kt = 0; kt < 4; ++kt) {
            const float4* p4 = (const float4*)(wr + kt * 32 + lh * 8);
            float4 w0 = p4[0], w1 = p4[1];
            f16x8 bf;
            bf[0] = (_Float16)w0.x; bf[1] = (_Float16)w0.y;
            bf[2] = (_Float16)w0.z; bf[3] = (_Float16)w0.w;
            bf[4] = (_Float16)w1.x; bf[5] = (_Float16)w1.y;
            bf[6] = (_Float16)w1.z; bf[7] = (_Float16)w1.w;
            Bf[t2][kt] = bf;
        }
    }
    float cst = 0.f, mean_acc = 0.f, mx = -1e30f, last = 0.f;
    const int len = lengths[b];
    const bool ard = (c == 0);
    const bool wr16 = (lane < 16);
    f16x8 av[4];
#pragma unroll
    for (int kt = 0; kt < 4; ++kt) av[kt] = (f16x8){0, 0, 0, 0, 0, 0, 0, 0};

    // double-buffered gate prefetch: one 8B load/lane, 2 steps ahead
    f16x4 gp0 = (f16x4){0, 0, 0, 0}, gp1 = (f16x4){0, 0, 0, 0};
    if (wr16) {
        gp0 = *(const f16x4*)(g1 + ((size_t)0 * BB + b) * GG + un * 4);
        int t1i = (1 < len) ? 1 : 0;
        gp1 = *(const f16x4*)(g1 + ((size_t)t1i * BB + b) * GG + un * 4);
    }
    __syncthreads();

#define L1_STEP(T_, RB_, GP_)                                                     \
    do {                                                                          \
        if (ard) {                                                                \
            _Pragma("unroll") for (int kt = 0; kt < 4; ++kt)                      \
                av[kt] = *(const f16x8*)&Hb[RB_][kt * 32 + lh * 8];               \
        }                                                                         \
        f32x4 acc[4];                                                             \
        _Pragma("unroll") for (int t2 = 0; t2 < 4; ++t2) {                        \
            acc[t2][0] = (float)GP_[t2];                                          \
            acc[t2][1] = 0.f; acc[t2][2] = 0.f; acc[t2][3] = 0.f;                 \
        }                                                                         \
        if (wr16) {                                                               \
            int tp = ((T_) + 2 < len) ? (T_) + 2 : len - 1;                       \
            GP_ = *(const f16x4*)(g1 + ((size_t)tp * BB + b) * GG + un * 4);      \
        }                                                                         \
        _Pragma("unroll") for (int t2 = 0; t2 < 4; ++t2) {                        \
            _Pragma("unroll") for (int kt = 0; kt < 4; ++kt)                      \
                acc[t2] = __builtin_amdgcn_mfma_f32_16x16x32_f16(                 \
                    av[kt], Bf[t2][kt], acc[t2], 0, 0, 0);                        \
        }                                                                         \
        float gi = sigm(acc[0][0]), gf = sigm(acc[1][0]);                         \
        float gg = tanh_f(acc[2][0]), go = sigm(acc[3][0]);                       \
        cst = gf * cst + gi * gg;                                                 \
        float hn = go * tanh_f(cst);                                              \
        if (wr16) Hb[(RB_) ^ 1][un] = (_Float16)hn;                               \
        mean_acc += hn;                                                           \
        mx = fmaxf(mx, hn);                                                       \
        if ((T_) == len - 1) last = hn;                                           \
        bar_lds();                                                                \
    } while (0)

    int t = 0;
    for (; t + 1 < len; t += 2) {
        L1_STEP(t, 0, gp0);
        L1_STEP(t + 1, 1, gp1);
    }
    if (t < len) L1_STEP(t, 0, gp0);
#undef L1_STEP

    if (wr16) {
        pooled[b * 384 + un] = mean_acc / (float)len;
        pooled[b * 384 + 128 + un] = mx;
        pooled[b * 384 + 256 + un] = last;
    }
}

// ---------------- head: [B,3H] @ [3H,C]^T + bias ----------------
__global__ __launch_bounds__(448) void k_head(
    const float* __restrict__ pooled, const float* __restrict__ lin_w,
    const float* __restrict__ lin_b, float* __restrict__ out) {
    int tid = threadIdx.x;  // 448 = 64*7
    int b = tid / 7, cc = tid % 7;
    const float* p = pooled + b * 384;
    const float* wr = lin_w + cc * 384;
    float a0 = 0.f, a1 = 0.f, a2 = 0.f, a3 = 0.f;
#pragma unroll
    for (int k = 0; k < 384; k += 4) {
        a0 += p[k + 0] * wr[k + 0];
        a1 += p[k + 1] * wr[k + 1];
        a2 += p[k + 2] * wr[k + 2];
        a3 += p[k + 3] * wr[k + 3];
    }
    out[tid] = lin_b[cc] + ((a0 + a1) + (a2 + a3));
}

extern "C" void kernel_launch(void* const* d_in, const int* in_sizes, int n_in,
                              void* d_out, int out_size, void* d_ws, size_t ws_size,
                              hipStream_t stream) {
    const float* x     = (const float*)d_in[0];
    const int*   lens  = (const int*)d_in[1];
    const float* ff_w  = (const float*)d_in[2];
    const float* ff_b  = (const float*)d_in[3];
    const float* W_ih0 = (const float*)d_in[4];
    const float* W_hh0 = (const float*)d_in[5];
    const float* b0    = (const float*)d_in[6];
    const float* W_ih1 = (const float*)d_in[7];
    const float* W_hh1 = (const float*)d_in[8];
    const float* b1    = (const float*)d_in[9];
    const float* lin_w = (const float*)d_in[10];
    const float* lin_b = (const float*)d_in[11];
    float* out = (float*)d_out;

    char* ws = (char*)d_ws;
    _Float16* h1 = (_Float16*)ws;                                   // [T*B][128] fp16 = 32 MB
    _Float16* g1 = (_Float16*)(ws + (size_t)TT * BB * HH * 2);      // [T*B][512] fp16 = 128 MB
    float* pooled = (float*)(ws + (size_t)TT * BB * HH * 2 + (size_t)TT * BB * GG * 2);

    k_lstm0<<<dim3(BB), dim3(512), 0, stream>>>(x, lens, ff_w, ff_b, W_ih0, W_hh0, b0, h1);
    k_proj<<<dim3((TT * BB) / 64, GG / 64), dim3(256), 0, stream>>>(
        (const __half*)h1, W_ih1, b1, (__half*)g1);
    k_lstm1<<<dim3(BB), dim3(512), 0, stream>>>(g1, lens, W_hh1, pooled);
    k_head<<<dim3(1), dim3(448), 0, stream>>>(pooled, lin_w, lin_b, out);
}